// Round 4
// baseline (3246.569 us; speedup 1.0000x reference)
//
#include <hip/hip_runtime.h>
#include <hip/hip_bf16.h>
#include <cstdint>

#define AS1 __attribute__((address_space(1)))
#define AS3 __attribute__((address_space(3)))

typedef float f32x4 __attribute__((ext_vector_type(4)));
typedef __bf16 bf16x8 __attribute__((ext_vector_type(8)));
typedef unsigned short u16x8 __attribute__((ext_vector_type(8)));
typedef unsigned short u16x4 __attribute__((ext_vector_type(4)));

constexpr int BDIM = 4096;   // batch rows (M)
constexpr int FDIM = 4096;   // features  (K)
constexpr int ODIM = 32000;  // out cols  (N)

__device__ __forceinline__ unsigned short f2bf(float f) {
  __bf16 h = (__bf16)f;               // RNE
  return __builtin_bit_cast(unsigned short, h);
}
__device__ __forceinline__ float bf2f(unsigned short u) {
  return (float)__builtin_bit_cast(__bf16, u);
}

__device__ __forceinline__ void gload16(const unsigned short* g, unsigned short* l) {
  __builtin_amdgcn_global_load_lds((const AS1 unsigned int*)(uintptr_t)g,
                                   (AS3 unsigned int*)(uintptr_t)l, 16, 0, 0);
}

// ---------------- prep A: a = x - mask; split into bf16 hi/lo planes --------
__global__ __launch_bounds__(256) void kprep_a(const float* __restrict__ x,
                                               const float* __restrict__ mk,
                                               unsigned short* __restrict__ hi,
                                               unsigned short* __restrict__ lo) {
  size_t idx = (size_t)blockIdx.x * 256 + threadIdx.x;  // one float4 per thread
  float4 xv = ((const float4*)x)[idx];
  float4 mv = ((const float4*)mk)[idx];
  float a[4] = {xv.x - mv.x, xv.y - mv.y, xv.z - mv.z, xv.w - mv.w};
  u16x4 h, l;
#pragma unroll
  for (int i = 0; i < 4; ++i) {
    unsigned short hb = f2bf(a[i]);
    h[i] = hb;
    l[i] = f2bf(a[i] - bf2f(hb));
  }
  *(u16x4*)(hi + idx * 4) = h;
  *(u16x4*)(lo + idx * 4) = l;
}

// ---------------- prep B: b = quant_w(w) - mask  (exact in bf16) ------------
__global__ __launch_bounds__(256) void kprep_b(const float* __restrict__ wgt,
                                               const float* __restrict__ mk,
                                               unsigned short* __restrict__ bq) {
  size_t idx = (size_t)blockIdx.x * 256 + threadIdx.x;  // one float4 per thread
  float4 wv = ((const float4*)wgt)[idx];
  float4 mv = ((const float4*)mk)[idx];
  float wa[4] = {wv.x, wv.y, wv.z, wv.w};
  float ma[4] = {mv.x, mv.y, mv.z, mv.w};
  u16x4 o;
#pragma unroll
  for (int i = 0; i < 4; ++i) {
    float q = rintf(wa[i] * 128.0f) * 0.0078125f;   // round-half-even, exact /128
    q = fminf(fmaxf(q, -1.0f), 1.0f);
    o[i] = f2bf(q - ma[i]);                          // integer/128, |int|<=141 -> exact
  }
  *(u16x4*)(bq + idx * 4) = o;
}

// ---------------- GEMM: C[m][n] = sum_k (ahi+alo)[m][k] * b[n][k] -----------
// 128x128 tile, BK=64, 4 waves (2x2), 16x16x32 bf16 MFMA, global_load_lds w=16.
// LDS kept linear; XOR slot swizzle (slot ^= row&7) applied on the GLOBAL src
// address at staging time and on the ds_read address at fragment time
// (both-sides-or-neither, guide §5 rule 21).
__global__ __launch_bounds__(256) void kgemm(const unsigned short* __restrict__ Ahi,
                                             const unsigned short* __restrict__ Alo,
                                             const unsigned short* __restrict__ Bq,
                                             float* __restrict__ C) {
  constexpr int BM = 128, BN = 128, BK = 64;
  constexpr int NTN = ODIM / BN;  // 250
  __shared__ __align__(16) unsigned short sAh[BM * BK];
  __shared__ __align__(16) unsigned short sAl[BM * BK];
  __shared__ __align__(16) unsigned short sB[BM * BK];

  int bid = blockIdx.x;
  int swz = (bid & 7) * ((int)gridDim.x >> 3) + (bid >> 3);  // 8000 % 8 == 0: bijective
  int bm = swz / NTN, bn = swz % NTN;

  int t = threadIdx.x;
  int w = t >> 6, l = t & 63;
  int wr = w >> 1, wc = w & 1;

  const unsigned short* ga = Ahi + (size_t)bm * BM * FDIM;
  const unsigned short* gl = Alo + (size_t)bm * BM * FDIM;
  const unsigned short* gb = Bq  + (size_t)bn * BN * FDIM;

  int srow = t >> 3;   // 0..31 within issue (8 lanes cover one 128B row)
  int sslot = t & 7;

  f32x4 acc[4][4] = {};

  for (int k0 = 0; k0 < FDIM; k0 += BK) {
    __syncthreads();
#pragma unroll
    for (int i = 0; i < 4; ++i) {
      int row = i * 32 + srow;                 // tile row 0..127
      int sp = sslot ^ (row & 7);              // pre-swizzled source slot
      int go = row * FDIM + k0 + sp * 8;       // element offset
      int lb = i * 2048 + w * 512;             // wave-uniform LDS base (ushorts)
      gload16(ga + go, &sAh[lb]);
      gload16(gl + go, &sAl[lb]);
      gload16(gb + go, &sB[lb]);
    }
    __syncthreads();
#pragma unroll
    for (int s = 0; s < 2; ++s) {              // two K=32 steps per staged tile
      bf16x8 fah[4], fal[4], fb[4];
#pragma unroll
      for (int f = 0; f < 4; ++f) {
        int ra = wr * 64 + f * 16 + (l & 15);
        int sa = ((s * 4 + (l >> 4)) ^ (ra & 7)) * 8;
        fah[f] = __builtin_bit_cast(bf16x8, *(const u16x8*)&sAh[ra * 64 + sa]);
        fal[f] = __builtin_bit_cast(bf16x8, *(const u16x8*)&sAl[ra * 64 + sa]);
        int rb = wc * 64 + f * 16 + (l & 15);
        int sb_ = ((s * 4 + (l >> 4)) ^ (rb & 7)) * 8;
        fb[f] = __builtin_bit_cast(bf16x8, *(const u16x8*)&sB[rb * 64 + sb_]);
      }
#pragma unroll
      for (int fm = 0; fm < 4; ++fm)
#pragma unroll
        for (int fn = 0; fn < 4; ++fn) {
          acc[fm][fn] = __builtin_amdgcn_mfma_f32_16x16x32_bf16(fah[fm], fb[fn], acc[fm][fn], 0, 0, 0);
          acc[fm][fn] = __builtin_amdgcn_mfma_f32_16x16x32_bf16(fal[fm], fb[fn], acc[fm][fn], 0, 0, 0);
        }
    }
  }

  // C/D layout (verified m89/m91): col = lane&15, row = (lane>>4)*4 + reg
  float* Cb = C + (size_t)(bm * BM + wr * 64) * ODIM + bn * BN + wc * 64;
  int cr = (l >> 4) * 4, cc = l & 15;
#pragma unroll
  for (int fm = 0; fm < 4; ++fm)
#pragma unroll
    for (int fn = 0; fn < 4; ++fn)
#pragma unroll
      for (int j = 0; j < 4; ++j)
        Cb[(size_t)(fm * 16 + cr + j) * ODIM + fn * 16 + cc] = acc[fm][fn][j];
}

// ---------------- row stats: online max + sum(exp) --------------------------
__global__ __launch_bounds__(256) void krowstat(const float* __restrict__ C,
                                                float* __restrict__ rmax,
                                                float* __restrict__ rinv) {
  int r = blockIdx.x;
  const float* row = C + (size_t)r * ODIM;
  float m = -3.4e38f, s = 0.f;
  for (int c = threadIdx.x; c < ODIM; c += 256) {  // 125 iters, coalesced
    float v = row[c];
    float nm = fmaxf(m, v);
    s = s * __expf(m - nm) + __expf(v - nm);
    m = nm;
  }
  for (int o = 32; o; o >>= 1) {
    float om = __shfl_xor(m, o);
    float os = __shfl_xor(s, o);
    float nm = fmaxf(m, om);
    s = s * __expf(m - nm) + os * __expf(om - nm);
    m = nm;
  }
  __shared__ float sm[4], ss[4];
  int w = threadIdx.x >> 6, l = threadIdx.x & 63;
  if (l == 0) { sm[w] = m; ss[w] = s; }
  __syncthreads();
  if (threadIdx.x == 0) {
    float M = sm[0], S = ss[0];
#pragma unroll
    for (int i = 1; i < 4; ++i) {
      float nm = fmaxf(M, sm[i]);
      S = S * __expf(M - nm) + ss[i] * __expf(sm[i] - nm);
      M = nm;
    }
    rmax[r] = M;
    rinv[r] = 1.0f / S;
  }
}

// ---------------- normalize in place ----------------------------------------
__global__ __launch_bounds__(256) void knorm(float* __restrict__ C,
                                             const float* __restrict__ rmax,
                                             const float* __restrict__ rinv,
                                             size_t n4) {
  size_t idx = (size_t)blockIdx.x * 256 + threadIdx.x;  // one float4 per thread
  if (idx >= n4) return;
  int r = (int)(idx / (ODIM / 4));
  float m = rmax[r], s = rinv[r];
  float4 v = ((const float4*)C)[idx];
  v.x = __expf(v.x - m) * s;
  v.y = __expf(v.y - m) * s;
  v.z = __expf(v.z - m) * s;
  v.w = __expf(v.w - m) * s;
  ((float4*)C)[idx] = v;
}

extern "C" void kernel_launch(void* const* d_in, const int* in_sizes, int n_in,
                              void* d_out, int out_size, void* d_ws, size_t ws_size,
                              hipStream_t stream) {
  const float* x = (const float*)d_in[0];
  const float* wgt = (const float*)d_in[1];
  const float* mask = (const float*)d_in[2];
  float* out = (float*)d_out;

  char* ws = (char*)d_ws;
  unsigned short* Ahi = (unsigned short*)ws;                          // 32 MiB
  unsigned short* Alo = Ahi + (size_t)BDIM * FDIM;                    // 32 MiB
  size_t a_bytes = (size_t)2 * BDIM * FDIM * 2;
  unsigned short* Bq = (unsigned short*)(ws + a_bytes);               // 250 MiB
  size_t bq_bytes = (size_t)ODIM * FDIM * 2;
  float* rmax = (float*)(ws + a_bytes + bq_bytes);
  float* rinv = rmax + BDIM;

  kprep_a<<<BDIM * (FDIM / (256 * 4)), 256, 0, stream>>>(x, mask, Ahi, Alo);
  kprep_b<<<(ODIM / 4) * (FDIM / 256), 256, 0, stream>>>(wgt, mask, Bq);  // 128000 blocks

  kgemm<<<(BDIM / 128) * (ODIM / 128), 256, 0, stream>>>(Ahi, Alo, Bq, out);

  krowstat<<<BDIM, 256, 0, stream>>>(out, rmax, rinv);

  size_t n4 = (size_t)BDIM * ODIM / 4;                 // 32,768,000 float4s
  int nblk = (int)((n4 + 255) / 256);                  // 128,000 exactly
  knorm<<<nblk, 256, 0, stream>>>(out, rmax, rinv, n4);
}